// Round 13
// baseline (258.299 us; speedup 1.0000x reference)
//
#include <hip/hip_runtime.h>

#define IYD 192
#define IZD 160
#define PLANE 30720        // IYD*IZD
#define VOLSZ 4915200      // 160*PLANE
#define YG 191
#define ZG 159

// LDS float layout (4508 floats = 18032 B):
// raw[2v][15 rows][44] @0 : z rel' 0..39 = global z0-4 .. z0+35 (quad-granular)
// ZB [2v][15][36] @1324  : z-box (with +1 z-shift semantics)
// DB [2v][15][36] @2404  : raw[min(w+4,159)]-raw[max(w-3,0)]
// TB [2v][8][32]  @3484  : y-box of ZB
// WB [2v][8][32]  @3996  : y-box of DB
#define RAWV 660
#define RAWR 44
#define ZBB 1324
#define DBB 2404
#define ZDV 540
#define ZDR 36
#define TBB 3484
#define WBB 3996
#define LDSF 4508

#define NVOX_INV (1.0f / 9657342.0f)   // 2*159*191*159

__global__ __launch_bounds__(256, 8) void grad_sim_v13(
    const float* __restrict__ Ii, const float* __restrict__ Ji,
    float* __restrict__ out)
{
    __shared__ __align__(16) float lds[LDSF];
    const int tid = threadIdx.x;
    const int z0 = (int)blockIdx.x * 32;
    const int y0 = (int)blockIdx.y * 8;
    const int seg = blockIdx.z & 7;
    const int bat = blockIdx.z >> 3;
    const int s0 = seg * 20;
    const int a0 = (seg == 0) ? 0 : (s0 - 3);
    const int aLast = (seg == 7) ? 159 : (s0 + 23);

    const float* __restrict__ bI = Ii + (size_t)bat * VOLSZ;
    const float* __restrict__ bJ = Ji + (size_t)bat * VOLSZ;

    // ---- per-thread float4 halo-load tasks: 2v x 15 rows x 10 quads = 300 ----
    const float* gq0;
    const float* gq1;
    int lq0, lq1;
    float mq0, mq1;
    {
        int q = tid;                       // task 0 (all threads)
        int v = q / 150;
        int rr = q - v * 150;
        int row = rr / 10;
        int qd = rr - row * 10;
        int iy = y0 - 3 + row;
        int izb = z0 - 4 + 4 * qd;
        bool ok = ((unsigned)iy < IYD) && (izb >= 0) && (izb + 3 <= 159);
        int iyc = min(max(iy, 0), IYD - 1);
        int izc = min(max(izb, 0), 156);
        gq0 = (v ? bJ : bI) + (iyc * IZD + izc);
        lq0 = v * RAWV + row * RAWR + 4 * qd;
        mq0 = ok ? 1.f : 0.f;
    }
    {
        int q = 256 + tid;                 // task 1 (tid < 44)
        int v = q / 150;
        int rr = q - v * 150;
        int row = rr / 10;
        int qd = rr - row * 10;
        int iy = y0 - 3 + row;
        int izb = z0 - 4 + 4 * qd;
        bool ok = ((unsigned)iy < IYD) && (izb >= 0) && (izb + 3 <= 159);
        int iyc = min(max(iy, 0), IYD - 1);
        int izc = min(max(izb, 0), 156);
        gq1 = (v ? bJ : bI) + (iyc * IZD + izc);
        lq1 = v * RAWV + row * RAWR + 4 * qd;
        mq1 = ok ? 1.f : 0.f;
    }

    // ---- E1 decode (120 lanes): (vol, row 0..14, zq 0..3) ----
    const int zv = tid / 60;
    const int zrr = tid - 60 * zv;
    const int zr = zrr >> 2;
    const int zq = zrr & 3;
    const bool doZ = tid < 120;
    const bool zlo = (z0 == 0) && (zq == 0);
    const bool zhi = (z0 == 128) && (zq == 3);
    const int rawRd = zv * RAWV + zr * RAWR + 8 * zq;
    const int zdWr = zv * ZDV + zr * ZDR + 8 * zq;

    // ---- E2 decode (64 lanes): (half, zq4 0..7, f 0..1, v 0..1) ----
    const int e2half = tid & 1;
    const int e2c = tid >> 1;              // 0..31
    const int e2zq = e2c & 7;
    const int e2f = (e2c >> 3) & 1;
    const int e2v = e2c >> 4;
    const bool doY = tid < 64;
    const int e2base = (e2f ? DBB : ZBB) + e2v * ZDV + 4 * e2zq;
    const int e2out = (e2f ? WBB : TBB) + e2v * 256 + 4 * e2zq;
    const float mlo = (y0 == 0) ? 0.f : 1.f;
    const float mhi = (y0 == 184) ? 0.f : 1.f;

    // ---- E3 per-thread column ----
    const int oy = tid >> 5;
    const int oz = tid & 31;
    const int ygl = y0 + oy;
    const int vmax = min(3, 190 - ygl);
    const int vmin = max(-3, -ygl);
    const int vHiI = ZBB + (oy + vmax + 4) * ZDR + oz;
    const int vLoI = ZBB + (oy + vmin + 3) * ZDR + oz;
    const bool okyz = (ygl < YG) && ((z0 + oz) < ZG);

    // x rings (static indices only)
    float Tr[2][8], Vr[2][8], Wr[2][8], Sdy[2], Sdz[2];
#pragma unroll
    for (int v = 0; v < 2; ++v) {
#pragma unroll
        for (int j = 0; j < 8; ++j) { Tr[v][j] = 0.f; Vr[v][j] = 0.f; Wr[v][j] = 0.f; }
        Sdy[v] = 0.f; Sdz[v] = 0.f;
    }
    float acc = 0.f;

    // ---- prologue: land raw plane a0 ----
    {
        const size_t pb = (size_t)a0 * PLANE;
        float4 t0 = *(const float4*)(gq0 + pb);
        t0.x *= mq0; t0.y *= mq0; t0.z *= mq0; t0.w *= mq0;
        *(float4*)&lds[lq0] = t0;
        if (tid < 44) {
            float4 t1 = *(const float4*)(gq1 + pb);
            t1.x *= mq1; t1.y *= mq1; t1.z *= mq1; t1.w *= mq1;
            *(float4*)&lds[lq1] = t1;
        }
    }
    __syncthreads();

    for (int ag = (a0 & ~7); ag <= aLast; ag += 8) {
#pragma unroll
        for (int u = 0; u < 8; ++u) {
            const int a = ag + u;
            if (a < a0 || a > aLast) continue;   // uniform

            // ---- issue prefetch of plane a+1 ----
            const bool dof = (a + 1) <= aLast;
            float4 pf0, pf1;
            if (dof) {
                const size_t pb = (size_t)(a + 1) * PLANE;
                pf0 = *(const float4*)(gq0 + pb);
                if (tid < 44) pf1 = *(const float4*)(gq1 + pb);
            }

            // ---- E1: z-stage plane a -> ZB/DB ----
            if (doZ) {
                float C[16];
                const float4* rb = (const float4*)&lds[rawRd];
#pragma unroll
                for (int q = 0; q < 4; ++q) ((float4*)C)[q] = rb[q];
                float D[8];
#pragma unroll
                for (int i = 0; i < 8; ++i) D[i] = C[i + 8] - C[i + 1];
                if (zlo) { D[0] = C[8] - C[4]; D[1] = C[9] - C[4]; D[2] = C[10] - C[4]; }
                if (zhi) { D[4] = C[11] - C[5]; D[5] = C[11] - C[6];
                           D[6] = C[11] - C[7]; D[7] = C[11] - C[8]; }
                if (zlo) { C[2] = 0.f; C[3] = 0.f; C[4] = 0.f; }
                float Z[8];
                float w = C[2] + C[3] + C[4] + C[5] + C[6] + C[7] + C[8];
                Z[0] = w;
#pragma unroll
                for (int m = 1; m < 8; ++m) { w += C[m + 8] - C[m + 1]; Z[m] = w; }
                float4* zb = (float4*)&lds[ZBB + zdWr];
                zb[0] = make_float4(Z[0], Z[1], Z[2], Z[3]);
                zb[1] = make_float4(Z[4], Z[5], Z[6], Z[7]);
                float4* db = (float4*)&lds[DBB + zdWr];
                db[0] = make_float4(D[0], D[1], D[2], D[3]);
                db[1] = make_float4(D[4], D[5], D[6], D[7]);
            }
            __syncthreads();

            // ---- E2: y-slide in registers (b128 over z) ----
            if (doY) {
                float4 r[11];
                const int r0 = e2half ? 4 : 1;
#pragma unroll
                for (int i = 0; i < 11; ++i)
                    r[i] = *(const float4*)&lds[e2base + (r0 + i) * ZDR];
                if (e2half == 0) {
                    r[0].x *= mlo; r[0].y *= mlo; r[0].z *= mlo; r[0].w *= mlo;
                    r[1].x *= mlo; r[1].y *= mlo; r[1].z *= mlo; r[1].w *= mlo;
                    r[2].x *= mlo; r[2].y *= mlo; r[2].z *= mlo; r[2].w *= mlo;
                    r[10].x *= mhi; r[10].y *= mhi; r[10].z *= mhi; r[10].w *= mhi;
                    float4 w;
                    w.x = r[0].x + r[1].x + r[2].x + r[3].x + r[4].x + r[5].x + r[6].x;
                    w.y = r[0].y + r[1].y + r[2].y + r[3].y + r[4].y + r[5].y + r[6].y;
                    w.z = r[0].z + r[1].z + r[2].z + r[3].z + r[4].z + r[5].z + r[6].z;
                    w.w = r[0].w + r[1].w + r[2].w + r[3].w + r[4].w + r[5].w + r[6].w;
                    *(float4*)&lds[e2out] = w;
#pragma unroll
                    for (int m = 1; m < 4; ++m) {
                        w.x += r[m + 6].x - r[m - 1].x;
                        w.y += r[m + 6].y - r[m - 1].y;
                        w.z += r[m + 6].z - r[m - 1].z;
                        w.w += r[m + 6].w - r[m - 1].w;
                        *(float4*)&lds[e2out + m * 32] = w;
                    }
                } else {
                    r[7].x *= mhi; r[7].y *= mhi; r[7].z *= mhi; r[7].w *= mhi;
                    r[8].x *= mhi; r[8].y *= mhi; r[8].z *= mhi; r[8].w *= mhi;
                    r[9].x *= mhi; r[9].y *= mhi; r[9].z *= mhi; r[9].w *= mhi;
                    r[10].x *= mhi; r[10].y *= mhi; r[10].z *= mhi; r[10].w *= mhi;
                    float4 w;
                    w.x = r[1].x + r[2].x + r[3].x + r[4].x + r[5].x + r[6].x + r[7].x;
                    w.y = r[1].y + r[2].y + r[3].y + r[4].y + r[5].y + r[6].y + r[7].y;
                    w.z = r[1].z + r[2].z + r[3].z + r[4].z + r[5].z + r[6].z + r[7].z;
                    w.w = r[1].w + r[2].w + r[3].w + r[4].w + r[5].w + r[6].w + r[7].w;
                    *(float4*)&lds[e2out + 4 * 32] = w;
#pragma unroll
                    for (int m = 1; m < 4; ++m) {
                        w.x += r[m + 7].x - r[m].x;
                        w.y += r[m + 7].y - r[m].y;
                        w.z += r[m + 7].z - r[m].z;
                        w.w += r[m + 7].w - r[m].w;
                        *(float4*)&lds[e2out + (4 + m) * 32] = w;
                    }
                }
            }
            __syncthreads();

            // ---- E3: ring push + emit x = a-4 ----
            {
                float tI = lds[TBB + tid];
                float tJ = lds[TBB + 256 + tid];
                float wI = lds[WBB + tid];
                float wJ = lds[WBB + 256 + tid];
                float vI = lds[vHiI] - lds[vLoI];
                float vJ = lds[vHiI + ZDV] - lds[vLoI + ZDV];
                if (a == a0) { vI = 0.f; vJ = 0.f; wI = 0.f; wJ = 0.f; }
                const int p = u;                 // = a & 7, compile-time
                const int p1 = (u + 1) & 7;
                float hdxI = tI - Tr[0][p1];
                float hdxJ = tJ - Tr[1][p1];
                Sdy[0] += vI - Vr[0][p1]; Vr[0][p] = vI;
                Sdy[1] += vJ - Vr[1][p1]; Vr[1][p] = vJ;
                Sdz[0] += wI - Wr[0][p1]; Wr[0][p] = wI;
                Sdz[1] += wJ - Wr[1][p1]; Wr[1][p] = wJ;
                Tr[0][p] = tI; Tr[1][p] = tJ;
                if (p == 0 && a == 0) {   // seed clamped prefix T[0] for x=0,1,2
                    Tr[0][5] = tI; Tr[0][6] = tI; Tr[0][7] = tI;
                    Tr[1][5] = tJ; Tr[1][6] = tJ; Tr[1][7] = tJ;
                }
                if (a >= s0 + 4) {
                    float cross = fabsf(hdxI * hdxJ + Sdy[0] * Sdy[1] + Sdz[0] * Sdz[1]) + 0.01f;
                    float dI = hdxI * hdxI + Sdy[0] * Sdy[0] + Sdz[0] * Sdz[0] + 0.01f;
                    float dJ = hdxJ * hdxJ + Sdy[1] * Sdy[1] + Sdz[1] * Sdz[1] + 0.01f;
                    float val = cross * rsqrtf(dI * dJ);
                    if (okyz) acc += val;
                }
            }

            // ---- land prefetch into raw (E1 of plane a is done) ----
            if (dof) {
                pf0.x *= mq0; pf0.y *= mq0; pf0.z *= mq0; pf0.w *= mq0;
                *(float4*)&lds[lq0] = pf0;
                if (tid < 44) {
                    pf1.x *= mq1; pf1.y *= mq1; pf1.z *= mq1; pf1.w *= mq1;
                    *(float4*)&lds[lq1] = pf1;
                }
            }
            __syncthreads();
        }
    }

    // ---- register-only tail (seg 7): x = 156,157,158 ----
    if (seg == 7) {
#pragma unroll
        for (int tt = 0; tt < 3; ++tt) {
            const int sl = tt + 1;               // planes 153,154,155
            float hdxI = Tr[0][7] - Tr[0][sl];   // T[159] - T[x-3]
            float hdxJ = Tr[1][7] - Tr[1][sl];
            Sdy[0] -= Vr[0][sl]; Sdy[1] -= Vr[1][sl];
            Sdz[0] -= Wr[0][sl]; Sdz[1] -= Wr[1][sl];
            float cross = fabsf(hdxI * hdxJ + Sdy[0] * Sdy[1] + Sdz[0] * Sdz[1]) + 0.01f;
            float dI = hdxI * hdxI + Sdy[0] * Sdy[0] + Sdz[0] * Sdz[0] + 0.01f;
            float dJ = hdxJ * hdxJ + Sdy[1] * Sdy[1] + Sdz[1] * Sdz[1] + 0.01f;
            float val = cross * rsqrtf(dI * dJ);
            if (okyz) acc += val;
        }
    }

    // ---- block reduce + atomic ----
#pragma unroll
    for (int off = 32; off > 0; off >>= 1) acc += __shfl_down(acc, off, 64);
    __syncthreads();
    if ((tid & 63) == 0) lds[tid >> 6] = acc;
    __syncthreads();
    if (tid == 0)
        atomicAdd(out, (lds[0] + lds[1] + lds[2] + lds[3]) * NVOX_INV);
}

extern "C" void kernel_launch(void* const* d_in, const int* in_sizes, int n_in,
                              void* d_out, int out_size, void* d_ws, size_t ws_size,
                              hipStream_t stream) {
    const float* Ii = (const float*)d_in[0];
    const float* Ji = (const float*)d_in[1];
    float* out = (float*)d_out;
    hipMemsetAsync(d_out, 0, sizeof(float) * (out_size > 0 ? out_size : 1), stream);
    dim3 grid(5, 24, 16);   // z-tiles(32) x y-tiles(8) x (8 x-segments * 2 batches)
    grad_sim_v13<<<grid, dim3(256), 0, stream>>>(Ii, Ji, out);
}

// Round 14
// 91.861 us; speedup vs baseline: 2.8119x; 2.8119x over previous
//
#include <hip/hip_runtime.h>

#define IYD 192
#define IZD 160
#define PLANE 30720        // IYD*IZD
#define VOLSZ 4915200      // 160*PLANE
#define YG 191
#define ZG 159

// LDS float layout (4508 floats = 18032 B):
// raw[2v][15 rows][44] @0 : z rel' 0..39 = global z0-4 .. z0+35 (quad-granular)
// ZB [2v][15][36] @1324  : z-box (with +1 z-shift semantics)
// DB [2v][15][36] @2404  : raw[min(w+4,159)]-raw[max(w-3,0)]
// TB [2v][8][32]  @3484  : y-box of ZB
// WB [2v][8][32]  @3996  : y-box of DB
#define RAWV 660
#define RAWR 44
#define ZBB 1324
#define DBB 2404
#define ZDV 540
#define ZDR 36
#define TBB 3484
#define WBB 3996
#define LDSF 4508

#define NVOX_INV (1.0f / 9657342.0f)   // 2*159*191*159

__global__ __launch_bounds__(256, 4) void grad_sim_v14(
    const float* __restrict__ Ii, const float* __restrict__ Ji,
    float* __restrict__ out)
{
    __shared__ __align__(16) float lds[LDSF];
    const int tid = threadIdx.x;
    const int z0 = (int)blockIdx.x * 32;
    const int y0 = (int)blockIdx.y * 8;
    const int seg = blockIdx.z & 7;
    const int bat = blockIdx.z >> 3;
    const int s0 = seg * 20;
    const int a0 = (seg == 0) ? 0 : (s0 - 3);
    const int aLast = (seg == 7) ? 159 : (s0 + 23);

    const float* __restrict__ bI = Ii + (size_t)bat * VOLSZ;
    const float* __restrict__ bJ = Ji + (size_t)bat * VOLSZ;

    // ---- per-thread float4 halo-load tasks: 2v x 15 rows x 10 quads = 300 ----
    const float* gq0;
    const float* gq1;
    int lq0, lq1;
    float mq0, mq1;
    {
        int q = tid;                       // task 0 (all threads)
        int v = q / 150;
        int rr = q - v * 150;
        int row = rr / 10;
        int qd = rr - row * 10;
        int iy = y0 - 3 + row;
        int izb = z0 - 4 + 4 * qd;
        bool ok = ((unsigned)iy < IYD) && (izb >= 0) && (izb + 3 <= 159);
        int iyc = min(max(iy, 0), IYD - 1);
        int izc = min(max(izb, 0), 156);
        gq0 = (v ? bJ : bI) + (iyc * IZD + izc);
        lq0 = v * RAWV + row * RAWR + 4 * qd;
        mq0 = ok ? 1.f : 0.f;
    }
    {
        int q = 256 + tid;                 // task 1 (tid < 44)
        int v = q / 150;
        int rr = q - v * 150;
        int row = rr / 10;
        int qd = rr - row * 10;
        int iy = y0 - 3 + row;
        int izb = z0 - 4 + 4 * qd;
        bool ok = ((unsigned)iy < IYD) && (izb >= 0) && (izb + 3 <= 159);
        int iyc = min(max(iy, 0), IYD - 1);
        int izc = min(max(izb, 0), 156);
        gq1 = (v ? bJ : bI) + (iyc * IZD + izc);
        lq1 = v * RAWV + row * RAWR + 4 * qd;
        mq1 = ok ? 1.f : 0.f;
    }

    // ---- E1 decode (120 lanes): (vol, row 0..14, zq 0..3) ----
    const int zv = tid / 60;
    const int zrr = tid - 60 * zv;
    const int zr = zrr >> 2;
    const int zq = zrr & 3;
    const bool doZ = tid < 120;
    const bool zlo = (z0 == 0) && (zq == 0);
    const bool zhi = (z0 == 128) && (zq == 3);
    const int rawRd = zv * RAWV + zr * RAWR + 8 * zq;
    const int zdWr = zv * ZDV + zr * ZDR + 8 * zq;

    // ---- E2 decode (64 lanes): (half, zq4 0..7, f 0..1, v 0..1) ----
    const int e2half = tid & 1;
    const int e2c = tid >> 1;              // 0..31
    const int e2zq = e2c & 7;
    const int e2f = (e2c >> 3) & 1;
    const int e2v = e2c >> 4;
    const bool doY = tid < 64;
    const int e2base = (e2f ? DBB : ZBB) + e2v * ZDV + 4 * e2zq;
    const int e2out = (e2f ? WBB : TBB) + e2v * 256 + 4 * e2zq;
    const float mlo = (y0 == 0) ? 0.f : 1.f;
    const float mhi = (y0 == 184) ? 0.f : 1.f;

    // ---- E3 per-thread column ----
    const int oy = tid >> 5;
    const int oz = tid & 31;
    const int ygl = y0 + oy;
    const int vmax = min(3, 190 - ygl);
    const int vmin = max(-3, -ygl);
    const int vHiI = ZBB + (oy + vmax + 4) * ZDR + oz;
    const int vLoI = ZBB + (oy + vmin + 3) * ZDR + oz;
    const bool okyz = (ygl < YG) && ((z0 + oz) < ZG);

    // x rings (static indices only)
    float Tr[2][8], Vr[2][8], Wr[2][8], Sdy[2], Sdz[2];
#pragma unroll
    for (int v = 0; v < 2; ++v) {
#pragma unroll
        for (int j = 0; j < 8; ++j) { Tr[v][j] = 0.f; Vr[v][j] = 0.f; Wr[v][j] = 0.f; }
        Sdy[v] = 0.f; Sdz[v] = 0.f;
    }
    float acc = 0.f;

    // ---- prologue: land raw plane a0 ----
    {
        const size_t pb = (size_t)a0 * PLANE;
        float4 t0 = *(const float4*)(gq0 + pb);
        t0.x *= mq0; t0.y *= mq0; t0.z *= mq0; t0.w *= mq0;
        *(float4*)&lds[lq0] = t0;
        if (tid < 44) {
            float4 t1 = *(const float4*)(gq1 + pb);
            t1.x *= mq1; t1.y *= mq1; t1.z *= mq1; t1.w *= mq1;
            *(float4*)&lds[lq1] = t1;
        }
    }
    __syncthreads();

    for (int ag = (a0 & ~7); ag <= aLast; ag += 8) {
#pragma unroll
        for (int u = 0; u < 8; ++u) {
            const int a = ag + u;
            if (a < a0 || a > aLast) continue;   // uniform

            // ---- issue prefetch of plane a+1 ----
            const bool dof = (a + 1) <= aLast;
            float4 pf0, pf1;
            if (dof) {
                const size_t pb = (size_t)(a + 1) * PLANE;
                pf0 = *(const float4*)(gq0 + pb);
                if (tid < 44) pf1 = *(const float4*)(gq1 + pb);
            }

            // ---- E1: z-stage plane a -> ZB/DB ----
            if (doZ) {
                float C[16];
                const float4* rb = (const float4*)&lds[rawRd];
#pragma unroll
                for (int q = 0; q < 4; ++q) ((float4*)C)[q] = rb[q];
                float D[8];
#pragma unroll
                for (int i = 0; i < 8; ++i) D[i] = C[i + 8] - C[i + 1];
                if (zlo) { D[0] = C[8] - C[4]; D[1] = C[9] - C[4]; D[2] = C[10] - C[4]; }
                if (zhi) { D[4] = C[11] - C[5]; D[5] = C[11] - C[6];
                           D[6] = C[11] - C[7]; D[7] = C[11] - C[8]; }
                if (zlo) { C[2] = 0.f; C[3] = 0.f; C[4] = 0.f; }
                float Z[8];
                float w = C[2] + C[3] + C[4] + C[5] + C[6] + C[7] + C[8];
                Z[0] = w;
#pragma unroll
                for (int m = 1; m < 8; ++m) { w += C[m + 8] - C[m + 1]; Z[m] = w; }
                float4* zb = (float4*)&lds[ZBB + zdWr];
                zb[0] = make_float4(Z[0], Z[1], Z[2], Z[3]);
                zb[1] = make_float4(Z[4], Z[5], Z[6], Z[7]);
                float4* db = (float4*)&lds[DBB + zdWr];
                db[0] = make_float4(D[0], D[1], D[2], D[3]);
                db[1] = make_float4(D[4], D[5], D[6], D[7]);
            }
            __syncthreads();

            // ---- E2: y-slide in registers (b128 over z) ----
            if (doY) {
                float4 r[11];
                const int r0 = e2half ? 4 : 1;
#pragma unroll
                for (int i = 0; i < 11; ++i)
                    r[i] = *(const float4*)&lds[e2base + (r0 + i) * ZDR];
                if (e2half == 0) {
                    r[0].x *= mlo; r[0].y *= mlo; r[0].z *= mlo; r[0].w *= mlo;
                    r[1].x *= mlo; r[1].y *= mlo; r[1].z *= mlo; r[1].w *= mlo;
                    r[2].x *= mlo; r[2].y *= mlo; r[2].z *= mlo; r[2].w *= mlo;
                    r[10].x *= mhi; r[10].y *= mhi; r[10].z *= mhi; r[10].w *= mhi;
                    float4 w;
                    w.x = r[0].x + r[1].x + r[2].x + r[3].x + r[4].x + r[5].x + r[6].x;
                    w.y = r[0].y + r[1].y + r[2].y + r[3].y + r[4].y + r[5].y + r[6].y;
                    w.z = r[0].z + r[1].z + r[2].z + r[3].z + r[4].z + r[5].z + r[6].z;
                    w.w = r[0].w + r[1].w + r[2].w + r[3].w + r[4].w + r[5].w + r[6].w;
                    *(float4*)&lds[e2out] = w;
#pragma unroll
                    for (int m = 1; m < 4; ++m) {
                        w.x += r[m + 6].x - r[m - 1].x;
                        w.y += r[m + 6].y - r[m - 1].y;
                        w.z += r[m + 6].z - r[m - 1].z;
                        w.w += r[m + 6].w - r[m - 1].w;
                        *(float4*)&lds[e2out + m * 32] = w;
                    }
                } else {
                    r[7].x *= mhi; r[7].y *= mhi; r[7].z *= mhi; r[7].w *= mhi;
                    r[8].x *= mhi; r[8].y *= mhi; r[8].z *= mhi; r[8].w *= mhi;
                    r[9].x *= mhi; r[9].y *= mhi; r[9].z *= mhi; r[9].w *= mhi;
                    r[10].x *= mhi; r[10].y *= mhi; r[10].z *= mhi; r[10].w *= mhi;
                    float4 w;
                    w.x = r[1].x + r[2].x + r[3].x + r[4].x + r[5].x + r[6].x + r[7].x;
                    w.y = r[1].y + r[2].y + r[3].y + r[4].y + r[5].y + r[6].y + r[7].y;
                    w.z = r[1].z + r[2].z + r[3].z + r[4].z + r[5].z + r[6].z + r[7].z;
                    w.w = r[1].w + r[2].w + r[3].w + r[4].w + r[5].w + r[6].w + r[7].w;
                    *(float4*)&lds[e2out + 4 * 32] = w;
#pragma unroll
                    for (int m = 1; m < 4; ++m) {
                        w.x += r[m + 7].x - r[m].x;
                        w.y += r[m + 7].y - r[m].y;
                        w.z += r[m + 7].z - r[m].z;
                        w.w += r[m + 7].w - r[m].w;
                        *(float4*)&lds[e2out + (4 + m) * 32] = w;
                    }
                }
            }
            __syncthreads();

            // ---- E3: ring push + emit x = a-4 ----
            {
                float tI = lds[TBB + tid];
                float tJ = lds[TBB + 256 + tid];
                float wI = lds[WBB + tid];
                float wJ = lds[WBB + 256 + tid];
                float vI = lds[vHiI] - lds[vLoI];
                float vJ = lds[vHiI + ZDV] - lds[vLoI + ZDV];
                if (a == a0) { vI = 0.f; vJ = 0.f; wI = 0.f; wJ = 0.f; }
                const int p = u;                 // = a & 7, compile-time
                const int p1 = (u + 1) & 7;
                float hdxI = tI - Tr[0][p1];
                float hdxJ = tJ - Tr[1][p1];
                Sdy[0] += vI - Vr[0][p1]; Vr[0][p] = vI;
                Sdy[1] += vJ - Vr[1][p1]; Vr[1][p] = vJ;
                Sdz[0] += wI - Wr[0][p1]; Wr[0][p] = wI;
                Sdz[1] += wJ - Wr[1][p1]; Wr[1][p] = wJ;
                Tr[0][p] = tI; Tr[1][p] = tJ;
                if (p == 0 && a == 0) {   // seed clamped prefix T[0] for x=0,1,2
                    Tr[0][5] = tI; Tr[0][6] = tI; Tr[0][7] = tI;
                    Tr[1][5] = tJ; Tr[1][6] = tJ; Tr[1][7] = tJ;
                }
                if (a >= s0 + 4) {
                    float cross = fabsf(hdxI * hdxJ + Sdy[0] * Sdy[1] + Sdz[0] * Sdz[1]) + 0.01f;
                    float dI = hdxI * hdxI + Sdy[0] * Sdy[0] + Sdz[0] * Sdz[0] + 0.01f;
                    float dJ = hdxJ * hdxJ + Sdy[1] * Sdy[1] + Sdz[1] * Sdz[1] + 0.01f;
                    float val = cross * rsqrtf(dI * dJ);
                    if (okyz) acc += val;
                }
            }

            // ---- land prefetch into raw (E1 of plane a is done) ----
            if (dof) {
                pf0.x *= mq0; pf0.y *= mq0; pf0.z *= mq0; pf0.w *= mq0;
                *(float4*)&lds[lq0] = pf0;
                if (tid < 44) {
                    pf1.x *= mq1; pf1.y *= mq1; pf1.z *= mq1; pf1.w *= mq1;
                    *(float4*)&lds[lq1] = pf1;
                }
            }
            __syncthreads();
        }
    }

    // ---- register-only tail (seg 7): x = 156,157,158 ----
    if (seg == 7) {
#pragma unroll
        for (int tt = 0; tt < 3; ++tt) {
            const int sl = tt + 1;               // planes 153,154,155
            float hdxI = Tr[0][7] - Tr[0][sl];   // T[159] - T[x-3]
            float hdxJ = Tr[1][7] - Tr[1][sl];
            Sdy[0] -= Vr[0][sl]; Sdy[1] -= Vr[1][sl];
            Sdz[0] -= Wr[0][sl]; Sdz[1] -= Wr[1][sl];
            float cross = fabsf(hdxI * hdxJ + Sdy[0] * Sdy[1] + Sdz[0] * Sdz[1]) + 0.01f;
            float dI = hdxI * hdxI + Sdy[0] * Sdy[0] + Sdz[0] * Sdz[0] + 0.01f;
            float dJ = hdxJ * hdxJ + Sdy[1] * Sdy[1] + Sdz[1] * Sdz[1] + 0.01f;
            float val = cross * rsqrtf(dI * dJ);
            if (okyz) acc += val;
        }
    }

    // ---- block reduce + atomic ----
#pragma unroll
    for (int off = 32; off > 0; off >>= 1) acc += __shfl_down(acc, off, 64);
    __syncthreads();
    if ((tid & 63) == 0) lds[tid >> 6] = acc;
    __syncthreads();
    if (tid == 0)
        atomicAdd(out, (lds[0] + lds[1] + lds[2] + lds[3]) * NVOX_INV);
}

extern "C" void kernel_launch(void* const* d_in, const int* in_sizes, int n_in,
                              void* d_out, int out_size, void* d_ws, size_t ws_size,
                              hipStream_t stream) {
    const float* Ii = (const float*)d_in[0];
    const float* Ji = (const float*)d_in[1];
    float* out = (float*)d_out;
    hipMemsetAsync(d_out, 0, sizeof(float) * (out_size > 0 ? out_size : 1), stream);
    dim3 grid(5, 24, 16);   // z-tiles(32) x y-tiles(8) x (8 x-segments * 2 batches)
    grad_sim_v14<<<grid, dim3(256), 0, stream>>>(Ii, Ji, out);
}

// Round 15
// 77.554 us; speedup vs baseline: 3.3306x; 1.1845x over previous
//
#include <hip/hip_runtime.h>

#define IYD 192
#define IZD 160
#define PLANE 30720        // IYD*IZD
#define VOLSZ 4915200      // 160*PLANE
#define YG 191
#define ZG 159

// LDS float layout (4508 floats = 18032 B):
// raw[2v][15 rows][44] @0 : z rel' 0..39 = global z0-4 .. z0+35 (quad-granular)
// ZB [2v][15][36] @1324  : z-box (with +1 z-shift semantics)
// DB [2v][15][36] @2404  : raw[min(w+4,159)]-raw[max(w-3,0)]
// TB [2v][8][32]  @3484  : y-box of ZB
// WB [2v][8][32]  @3996  : y-box of DB
#define RAWV 660
#define RAWR 44
#define ZBB 1324
#define DBB 2404
#define ZDV 540
#define ZDR 36
#define TBB 3484
#define WBB 3996
#define LDSF 4508

#define NVOX_INV (1.0f / 9657342.0f)   // 2*159*191*159

__global__ __launch_bounds__(256, 4) void grad_sim_v15(
    const float* __restrict__ Ii, const float* __restrict__ Ji,
    float* __restrict__ out)
{
    __shared__ __align__(16) float lds[LDSF];
    const int tid = threadIdx.x;
    const int z0 = (int)blockIdx.x * 32;
    const int y0 = (int)blockIdx.y * 8;
    const int seg = blockIdx.z & 3;
    const int bat = blockIdx.z >> 2;
    const int s0 = seg * 40;
    const int a0 = (seg == 0) ? 0 : (s0 - 3);
    const int aLast = (seg == 3) ? 159 : (s0 + 43);

    const float* __restrict__ bI = Ii + (size_t)bat * VOLSZ;
    const float* __restrict__ bJ = Ji + (size_t)bat * VOLSZ;

    // ---- per-thread float4 halo-load tasks: 2v x 15 rows x 10 quads = 300 ----
    const float* gq0;
    const float* gq1;
    int lq0, lq1;
    float mq0, mq1;
    {
        int q = tid;                       // task 0 (all threads)
        int v = q / 150;
        int rr = q - v * 150;
        int row = rr / 10;
        int qd = rr - row * 10;
        int iy = y0 - 3 + row;
        int izb = z0 - 4 + 4 * qd;
        bool ok = ((unsigned)iy < IYD) && (izb >= 0) && (izb + 3 <= 159);
        int iyc = min(max(iy, 0), IYD - 1);
        int izc = min(max(izb, 0), 156);
        gq0 = (v ? bJ : bI) + (iyc * IZD + izc);
        lq0 = v * RAWV + row * RAWR + 4 * qd;
        mq0 = ok ? 1.f : 0.f;
    }
    {
        int q = 256 + tid;                 // task 1 (tid < 44)
        int v = q / 150;
        int rr = q - v * 150;
        int row = rr / 10;
        int qd = rr - row * 10;
        int iy = y0 - 3 + row;
        int izb = z0 - 4 + 4 * qd;
        bool ok = ((unsigned)iy < IYD) && (izb >= 0) && (izb + 3 <= 159);
        int iyc = min(max(iy, 0), IYD - 1);
        int izc = min(max(izb, 0), 156);
        gq1 = (v ? bJ : bI) + (iyc * IZD + izc);
        lq1 = v * RAWV + row * RAWR + 4 * qd;
        mq1 = ok ? 1.f : 0.f;
    }

    // ---- E1 decode (120 lanes): (vol, row 0..14, zq 0..3) ----
    const int zv = tid / 60;
    const int zrr = tid - 60 * zv;
    const int zr = zrr >> 2;
    const int zq = zrr & 3;
    const bool doZ = tid < 120;
    const bool zlo = (z0 == 0) && (zq == 0);
    const bool zhi = (z0 == 128) && (zq == 3);
    const int rawRd = zv * RAWV + zr * RAWR + 8 * zq;
    const int zdWr = zv * ZDV + zr * ZDR + 8 * zq;

    // ---- E2 decode (64 lanes): (half, zq4 0..7, f 0..1, v 0..1) ----
    const int e2half = tid & 1;
    const int e2c = tid >> 1;              // 0..31
    const int e2zq = e2c & 7;
    const int e2f = (e2c >> 3) & 1;
    const int e2v = e2c >> 4;
    const bool doY = tid < 64;
    const int e2base = (e2f ? DBB : ZBB) + e2v * ZDV + 4 * e2zq;
    const int e2out = (e2f ? WBB : TBB) + e2v * 256 + 4 * e2zq;
    const float mlo = (y0 == 0) ? 0.f : 1.f;
    const float mhi = (y0 == 184) ? 0.f : 1.f;

    // ---- E3 per-thread column ----
    const int oy = tid >> 5;
    const int oz = tid & 31;
    const int ygl = y0 + oy;
    const int vmax = min(3, 190 - ygl);
    const int vmin = max(-3, -ygl);
    const int vHiI = ZBB + (oy + vmax + 4) * ZDR + oz;
    const int vLoI = ZBB + (oy + vmin + 3) * ZDR + oz;
    const bool okyz = (ygl < YG) && ((z0 + oz) < ZG);

    // x rings (static indices only)
    float Tr[2][8], Vr[2][8], Wr[2][8], Sdy[2], Sdz[2];
#pragma unroll
    for (int v = 0; v < 2; ++v) {
#pragma unroll
        for (int j = 0; j < 8; ++j) { Tr[v][j] = 0.f; Vr[v][j] = 0.f; Wr[v][j] = 0.f; }
        Sdy[v] = 0.f; Sdz[v] = 0.f;
    }
    float acc = 0.f;

    // ---- prologue: land raw plane a0 ----
    {
        const size_t pb = (size_t)a0 * PLANE;
        float4 t0 = *(const float4*)(gq0 + pb);
        t0.x *= mq0; t0.y *= mq0; t0.z *= mq0; t0.w *= mq0;
        *(float4*)&lds[lq0] = t0;
        if (tid < 44) {
            float4 t1 = *(const float4*)(gq1 + pb);
            t1.x *= mq1; t1.y *= mq1; t1.z *= mq1; t1.w *= mq1;
            *(float4*)&lds[lq1] = t1;
        }
    }
    __syncthreads();

    for (int ag = (a0 & ~7); ag <= aLast; ag += 8) {
#pragma unroll
        for (int u = 0; u < 8; ++u) {
            const int a = ag + u;
            if (a < a0 || a > aLast) continue;   // uniform

            // ---- issue prefetch of plane a+1 ----
            const bool dof = (a + 1) <= aLast;
            float4 pf0, pf1;
            if (dof) {
                const size_t pb = (size_t)(a + 1) * PLANE;
                pf0 = *(const float4*)(gq0 + pb);
                if (tid < 44) pf1 = *(const float4*)(gq1 + pb);
            }

            // ---- E1: z-stage plane a -> ZB/DB ----
            if (doZ) {
                float C[16];
                const float4* rb = (const float4*)&lds[rawRd];
#pragma unroll
                for (int q = 0; q < 4; ++q) ((float4*)C)[q] = rb[q];
                float D[8];
#pragma unroll
                for (int i = 0; i < 8; ++i) D[i] = C[i + 8] - C[i + 1];
                if (zlo) { D[0] = C[8] - C[4]; D[1] = C[9] - C[4]; D[2] = C[10] - C[4]; }
                if (zhi) { D[4] = C[11] - C[5]; D[5] = C[11] - C[6];
                           D[6] = C[11] - C[7]; D[7] = C[11] - C[8]; }
                if (zlo) { C[2] = 0.f; C[3] = 0.f; C[4] = 0.f; }
                float Z[8];
                float w = C[2] + C[3] + C[4] + C[5] + C[6] + C[7] + C[8];
                Z[0] = w;
#pragma unroll
                for (int m = 1; m < 8; ++m) { w += C[m + 8] - C[m + 1]; Z[m] = w; }
                float4* zb = (float4*)&lds[ZBB + zdWr];
                zb[0] = make_float4(Z[0], Z[1], Z[2], Z[3]);
                zb[1] = make_float4(Z[4], Z[5], Z[6], Z[7]);
                float4* db = (float4*)&lds[DBB + zdWr];
                db[0] = make_float4(D[0], D[1], D[2], D[3]);
                db[1] = make_float4(D[4], D[5], D[6], D[7]);
            }
            __syncthreads();

            // ---- E2: y-slide in registers (b128 over z) ----
            if (doY) {
                float4 r[11];
                const int r0 = e2half ? 4 : 1;
#pragma unroll
                for (int i = 0; i < 11; ++i)
                    r[i] = *(const float4*)&lds[e2base + (r0 + i) * ZDR];
                if (e2half == 0) {
                    r[0].x *= mlo; r[0].y *= mlo; r[0].z *= mlo; r[0].w *= mlo;
                    r[1].x *= mlo; r[1].y *= mlo; r[1].z *= mlo; r[1].w *= mlo;
                    r[2].x *= mlo; r[2].y *= mlo; r[2].z *= mlo; r[2].w *= mlo;
                    r[10].x *= mhi; r[10].y *= mhi; r[10].z *= mhi; r[10].w *= mhi;
                    float4 w;
                    w.x = r[0].x + r[1].x + r[2].x + r[3].x + r[4].x + r[5].x + r[6].x;
                    w.y = r[0].y + r[1].y + r[2].y + r[3].y + r[4].y + r[5].y + r[6].y;
                    w.z = r[0].z + r[1].z + r[2].z + r[3].z + r[4].z + r[5].z + r[6].z;
                    w.w = r[0].w + r[1].w + r[2].w + r[3].w + r[4].w + r[5].w + r[6].w;
                    *(float4*)&lds[e2out] = w;
#pragma unroll
                    for (int m = 1; m < 4; ++m) {
                        w.x += r[m + 6].x - r[m - 1].x;
                        w.y += r[m + 6].y - r[m - 1].y;
                        w.z += r[m + 6].z - r[m - 1].z;
                        w.w += r[m + 6].w - r[m - 1].w;
                        *(float4*)&lds[e2out + m * 32] = w;
                    }
                } else {
                    r[7].x *= mhi; r[7].y *= mhi; r[7].z *= mhi; r[7].w *= mhi;
                    r[8].x *= mhi; r[8].y *= mhi; r[8].z *= mhi; r[8].w *= mhi;
                    r[9].x *= mhi; r[9].y *= mhi; r[9].z *= mhi; r[9].w *= mhi;
                    r[10].x *= mhi; r[10].y *= mhi; r[10].z *= mhi; r[10].w *= mhi;
                    float4 w;
                    w.x = r[1].x + r[2].x + r[3].x + r[4].x + r[5].x + r[6].x + r[7].x;
                    w.y = r[1].y + r[2].y + r[3].y + r[4].y + r[5].y + r[6].y + r[7].y;
                    w.z = r[1].z + r[2].z + r[3].z + r[4].z + r[5].z + r[6].z + r[7].z;
                    w.w = r[1].w + r[2].w + r[3].w + r[4].w + r[5].w + r[6].w + r[7].w;
                    *(float4*)&lds[e2out + 4 * 32] = w;
#pragma unroll
                    for (int m = 1; m < 4; ++m) {
                        w.x += r[m + 7].x - r[m].x;
                        w.y += r[m + 7].y - r[m].y;
                        w.z += r[m + 7].z - r[m].z;
                        w.w += r[m + 7].w - r[m].w;
                        *(float4*)&lds[e2out + (4 + m) * 32] = w;
                    }
                }
            }
            __syncthreads();

            // ---- E3: ring push + emit x = a-4 ----
            {
                float tI = lds[TBB + tid];
                float tJ = lds[TBB + 256 + tid];
                float wI = lds[WBB + tid];
                float wJ = lds[WBB + 256 + tid];
                float vI = lds[vHiI] - lds[vLoI];
                float vJ = lds[vHiI + ZDV] - lds[vLoI + ZDV];
                if (a == a0) { vI = 0.f; vJ = 0.f; wI = 0.f; wJ = 0.f; }
                const int p = u;                 // = a & 7, compile-time
                const int p1 = (u + 1) & 7;
                float hdxI = tI - Tr[0][p1];
                float hdxJ = tJ - Tr[1][p1];
                Sdy[0] += vI - Vr[0][p1]; Vr[0][p] = vI;
                Sdy[1] += vJ - Vr[1][p1]; Vr[1][p] = vJ;
                Sdz[0] += wI - Wr[0][p1]; Wr[0][p] = wI;
                Sdz[1] += wJ - Wr[1][p1]; Wr[1][p] = wJ;
                Tr[0][p] = tI; Tr[1][p] = tJ;
                if (p == 0 && a == 0) {   // seed clamped prefix T[0] for x=0,1,2
                    Tr[0][5] = tI; Tr[0][6] = tI; Tr[0][7] = tI;
                    Tr[1][5] = tJ; Tr[1][6] = tJ; Tr[1][7] = tJ;
                }
                if (a >= s0 + 4) {
                    float cross = fabsf(hdxI * hdxJ + Sdy[0] * Sdy[1] + Sdz[0] * Sdz[1]) + 0.01f;
                    float dI = hdxI * hdxI + Sdy[0] * Sdy[0] + Sdz[0] * Sdz[0] + 0.01f;
                    float dJ = hdxJ * hdxJ + Sdy[1] * Sdy[1] + Sdz[1] * Sdz[1] + 0.01f;
                    float val = cross * rsqrtf(dI * dJ);
                    if (okyz) acc += val;
                }
            }

            // ---- land prefetch into raw (E1 of plane a is done) ----
            if (dof) {
                pf0.x *= mq0; pf0.y *= mq0; pf0.z *= mq0; pf0.w *= mq0;
                *(float4*)&lds[lq0] = pf0;
                if (tid < 44) {
                    pf1.x *= mq1; pf1.y *= mq1; pf1.z *= mq1; pf1.w *= mq1;
                    *(float4*)&lds[lq1] = pf1;
                }
            }
            __syncthreads();
        }
    }

    // ---- register-only tail (seg 3): x = 156,157,158 ----
    if (seg == 3) {
#pragma unroll
        for (int tt = 0; tt < 3; ++tt) {
            const int sl = tt + 1;               // planes 153,154,155
            float hdxI = Tr[0][7] - Tr[0][sl];   // T[159] - T[x-3]
            float hdxJ = Tr[1][7] - Tr[1][sl];
            Sdy[0] -= Vr[0][sl]; Sdy[1] -= Vr[1][sl];
            Sdz[0] -= Wr[0][sl]; Sdz[1] -= Wr[1][sl];
            float cross = fabsf(hdxI * hdxJ + Sdy[0] * Sdy[1] + Sdz[0] * Sdz[1]) + 0.01f;
            float dI = hdxI * hdxI + Sdy[0] * Sdy[0] + Sdz[0] * Sdz[0] + 0.01f;
            float dJ = hdxJ * hdxJ + Sdy[1] * Sdy[1] + Sdz[1] * Sdz[1] + 0.01f;
            float val = cross * rsqrtf(dI * dJ);
            if (okyz) acc += val;
        }
    }

    // ---- block reduce + atomic ----
#pragma unroll
    for (int off = 32; off > 0; off >>= 1) acc += __shfl_down(acc, off, 64);
    __syncthreads();
    if ((tid & 63) == 0) lds[tid >> 6] = acc;
    __syncthreads();
    if (tid == 0)
        atomicAdd(out, (lds[0] + lds[1] + lds[2] + lds[3]) * NVOX_INV);
}

extern "C" void kernel_launch(void* const* d_in, const int* in_sizes, int n_in,
                              void* d_out, int out_size, void* d_ws, size_t ws_size,
                              hipStream_t stream) {
    const float* Ii = (const float*)d_in[0];
    const float* Ji = (const float*)d_in[1];
    float* out = (float*)d_out;
    hipMemsetAsync(d_out, 0, sizeof(float) * (out_size > 0 ? out_size : 1), stream);
    dim3 grid(5, 24, 8);   // z-tiles(32) x y-tiles(8) x (4 x-segments * 2 batches)
    grad_sim_v15<<<grid, dim3(256), 0, stream>>>(Ii, Ji, out);
}